// Round 4
// baseline (788.436 us; speedup 1.0000x reference)
//
#include <hip/hip_runtime.h>
#include <math.h>

// Problem constants
#define N_TOK  16384   // B*S
#define D_IN   1024
#define D_OUT  1024
#define N_CENT 1024

// GEMM tiling
#define BM 128
#define BN 128
#define BK 64
#define NTILE (N_CENT / BN)   // 8

// Margin: bf16 approx error on d2 max ~1.6e-2 over all pairs; TAU >= 2*maxerr
// guarantees (a) unique-path argmin exact, (b) candidate set {d2a <= gmin+TAU}
// contains the exact argmin. Same TAU passed R3 with absmax 0.
#define TAU 0.05f

typedef __attribute__((ext_vector_type(8))) short short8;
typedef __attribute__((ext_vector_type(4))) float float4v;
typedef unsigned int u32;
typedef unsigned short u16;

__device__ __forceinline__ void async_copy16(const void* g, void* l) {
    __builtin_amdgcn_global_load_lds(
        (const __attribute__((address_space(1))) u32*)g,
        (__attribute__((address_space(3))) u32*)l, 16, 0, 0);
}

__device__ __forceinline__ u16 f32_to_bf16_rne(float f) {
    u32 u = __float_as_uint(f);
    u32 r = (u + 0x7FFFu + ((u >> 16) & 1u)) >> 16;
    return (u16)r;
}

// ---------------------------------------------------------------------------
// Fused fp32->bf16 convert + row squared norm. One wave per row.
// ---------------------------------------------------------------------------
__global__ __launch_bounds__(256) void prep_kernel(
    const float* __restrict__ x, u16* __restrict__ xh,
    float* __restrict__ xsq, int nrows)
{
    const int wv = threadIdx.x >> 6;
    const int l  = threadIdx.x & 63;
    const int row = blockIdx.x * 4 + wv;
    if (row >= nrows) return;
    const float4* xr = (const float4*)(x + (size_t)row * D_IN);
    ushort4* hr = (ushort4*)(xh + (size_t)row * D_IN);
    float s = 0.f;
#pragma unroll
    for (int i = 0; i < 4; ++i) {
        float4 v = xr[l + i * 64];
        ushort4 o;
        o.x = f32_to_bf16_rne(v.x); o.y = f32_to_bf16_rne(v.y);
        o.z = f32_to_bf16_rne(v.z); o.w = f32_to_bf16_rne(v.w);
        hr[l + i * 64] = o;
        s += v.x * v.x + v.y * v.y + v.z * v.z + v.w * v.w;
    }
#pragma unroll
    for (int off = 32; off > 0; off >>= 1) s += __shfl_down(s, off);
    if (l == 0) xsq[row] = s;
}

// ---------------------------------------------------------------------------
// bf16 MFMA GEMM with fused per-tile top-2 argmin epilogue.
// 256 threads = 4 waves (2x2); wave = 64x64 subtile = 4x4 of 16x16x32 MFMA.
// LDS: 8-octet rows (128 B = full bank wrap), octet XOR swizzle by (row&7).
// Emits per (token, n-tile): top-2 (val,idx) lex + conservative cnt within
// TAU of tile min. SoA layout [tile][token] for coalescing.
// ---------------------------------------------------------------------------
__global__ __launch_bounds__(256, 4) void gemm_top2_kernel(
    const u16* __restrict__ Xh, const u16* __restrict__ Ch,
    const float* __restrict__ x_sq, const float* __restrict__ c_sq,
    float* __restrict__ pv1, int* __restrict__ pi1,
    float* __restrict__ pv2, int* __restrict__ pi2,
    int* __restrict__ pcnt)
{
    __shared__ __align__(16) u16 As[BM * BK];   // 16 KB
    __shared__ __align__(16) u16 Bs[BN * BK];   // 16 KB

    const int t  = threadIdx.x;
    const int w  = t >> 6;
    const int l  = t & 63;
    const int wi = w >> 1, wj = w & 1;
    const int m0 = blockIdx.x * BM;
    const int n0 = blockIdx.y * BN;
    const int quad = l >> 4;
    const int r15  = l & 15;

    float4v acc[4][4];
#pragma unroll
    for (int i = 0; i < 4; ++i)
#pragma unroll
        for (int j = 0; j < 4; ++j)
            acc[i][j] = (float4v){0.f, 0.f, 0.f, 0.f};

    for (int k0 = 0; k0 < D_IN; k0 += BK) {
        // 1024 16B slots per operand; slot s: row=s>>3, lds-oct=s&7,
        // global oct = (s&7)^(row&7).
#pragma unroll
        for (int r = 0; r < 4; ++r) {
            const int s   = r * 256 + t;
            const int row = s >> 3;
            const int q   = (s & 7) ^ (row & 7);
            async_copy16(Xh + (size_t)(m0 + row) * D_IN + k0 + q * 8, As + s * 8);
            async_copy16(Ch + (size_t)(n0 + row) * D_IN + k0 + q * 8, Bs + s * 8);
        }
        __syncthreads();
#pragma unroll
        for (int kk2 = 0; kk2 < 2; ++kk2) {
            short8 af[4], bfr[4];
#pragma unroll
            for (int i = 0; i < 4; ++i) {
                const int r = wi * 64 + i * 16 + r15;
                af[i] = *(const short8*)(As + (r * 8 + ((kk2 * 4 + quad) ^ (r & 7))) * 8);
            }
#pragma unroll
            for (int j = 0; j < 4; ++j) {
                const int r = wj * 64 + j * 16 + r15;
                bfr[j] = *(const short8*)(Bs + (r * 8 + ((kk2 * 4 + quad) ^ (r & 7))) * 8);
            }
#pragma unroll
            for (int i = 0; i < 4; ++i)
#pragma unroll
                for (int j = 0; j < 4; ++j)
                    acc[i][j] = __builtin_amdgcn_mfma_f32_16x16x32_bf16(
                        af[i], bfr[j], acc[i][j], 0, 0, 0);
        }
        __syncthreads();
    }

    // Epilogue arena reuses As (all LDS reads done after final barrier).
    float* redv1 = (float*)As;            // [128][2]
    int*   redi1 = (int*)(redv1 + 256);
    float* redv2 = (float*)(redi1 + 256);
    int*   redi2 = (int*)(redv2 + 256);
    int*   redc  = (int*)(redi2 + 256);   // total 5120 B

    const int nbase = n0 + wj * 64 + r15;
    float cq[4];
#pragma unroll
    for (int j = 0; j < 4; ++j) cq[j] = c_sq[nbase + j * 16];

#pragma unroll
    for (int i = 0; i < 4; ++i) {
#pragma unroll
        for (int reg = 0; reg < 4; ++reg) {
            const int rloc = wi * 64 + i * 16 + quad * 4 + reg;
            const float xq = x_sq[m0 + rloc];
            float d[4];
#pragma unroll
            for (int j = 0; j < 4; ++j)
                d[j] = (xq - 2.0f * acc[i][j][reg]) + cq[j];
            // thread-local top-2 (ascending n, lex)
            float v1 = d[0], v2 = INFINITY;
            int   i1 = nbase, i2 = 0x7fffffff;
#pragma unroll
            for (int j = 1; j < 4; ++j) {
                const int n = nbase + j * 16;
                if (d[j] < v1) { v2 = v1; i2 = i1; v1 = d[j]; i1 = n; }
                else if (d[j] < v2 || (d[j] == v2 && n < i2)) { v2 = d[j]; i2 = n; }
            }
            // butterfly top-2 merge across the 16-lane row group
#pragma unroll
            for (int off = 1; off < 16; off <<= 1) {
                const float ov1 = __shfl_xor(v1, off); const int oi1 = __shfl_xor(i1, off);
                const float ov2 = __shfl_xor(v2, off); const int oi2 = __shfl_xor(i2, off);
                if (ov1 < v1 || (ov1 == v1 && oi1 < i1)) {
                    if (v1 < ov2 || (v1 == ov2 && i1 < oi2)) { v2 = v1; i2 = i1; }
                    else { v2 = ov2; i2 = oi2; }
                    v1 = ov1; i1 = oi1;
                } else if (ov1 < v2 || (ov1 == v2 && oi1 < i2)) {
                    v2 = ov1; i2 = oi1;
                }
            }
            // conservative candidate count within TAU of (>= tile) min
            int cnt = 0;
#pragma unroll
            for (int j = 0; j < 4; ++j) cnt += (d[j] <= v1 + TAU) ? 1 : 0;
#pragma unroll
            for (int off = 1; off < 16; off <<= 1) cnt += __shfl_xor(cnt, off);
            if (r15 == 0) {
                redv1[rloc * 2 + wj] = v1; redi1[rloc * 2 + wj] = i1;
                redv2[rloc * 2 + wj] = v2; redi2[rloc * 2 + wj] = i2;
                redc [rloc * 2 + wj] = cnt;
            }
        }
    }
    __syncthreads();
    if (t < BM) {
        float av1 = redv1[t * 2], av2 = redv2[t * 2];
        int   ai1 = redi1[t * 2], ai2 = redi2[t * 2];
        const float bv1 = redv1[t * 2 + 1], bv2 = redv2[t * 2 + 1];
        const int   bi1 = redi1[t * 2 + 1], bi2 = redi2[t * 2 + 1];
        // merge half B's top-2 into A's
        if (bv1 < av1 || (bv1 == av1 && bi1 < ai1)) {
            if (av1 < bv2 || (av1 == bv2 && ai1 < bi2)) { av2 = av1; ai2 = ai1; }
            else { av2 = bv2; ai2 = bi2; }
            av1 = bv1; ai1 = bi1;
        } else if (bv1 < av2 || (bv1 == av2 && bi1 < ai2)) {
            av2 = bv1; ai2 = bi1;
        }
        const size_t o = (size_t)blockIdx.y * N_TOK + m0 + t;
        pv1[o] = av1; pi1[o] = ai1; pv2[o] = av2; pi2[o] = ai2;
        pcnt[o] = redc[t * 2] + redc[t * 2 + 1];
    }
}

// ---------------------------------------------------------------------------
// Per-token merge of NTILE tile summaries. Unique -> final idx; else build
// candidate list (or full-rescore sentinel ncand=0 on overflow).
// ---------------------------------------------------------------------------
__global__ __launch_bounds__(256) void reduce_kernel(
    const float* __restrict__ pv1, const int* __restrict__ pi1,
    const float* __restrict__ pv2, const int* __restrict__ pi2,
    const int* __restrict__ pcnt,
    int* __restrict__ idx_final, int* __restrict__ flagged,
    int* __restrict__ counter, int* __restrict__ ncand, int* __restrict__ cand)
{
    const int m = blockIdx.x * 256 + threadIdx.x;
    float tv1[NTILE], tv2[NTILE];
    int   ti1[NTILE], ti2[NTILE], tc[NTILE];
    float v1 = INFINITY, v2 = INFINITY;
    int   i1 = 0x7fffffff, i2 = 0x7fffffff;
#pragma unroll
    for (int q = 0; q < NTILE; ++q) {
        tv1[q] = pv1[q * N_TOK + m]; ti1[q] = pi1[q * N_TOK + m];
        tv2[q] = pv2[q * N_TOK + m]; ti2[q] = pi2[q * N_TOK + m];
        tc[q]  = pcnt[q * N_TOK + m];
        if (tv1[q] < v1 || (tv1[q] == v1 && ti1[q] < i1)) {
            if (v1 < tv2[q] || (v1 == tv2[q] && i1 < ti2[q])) { v2 = v1; i2 = i1; }
            else { v2 = tv2[q]; i2 = ti2[q]; }
            v1 = tv1[q]; i1 = ti1[q];
        } else {
            if (tv1[q] < v2 || (tv1[q] == v2 && ti1[q] < i2)) { v2 = tv1[q]; i2 = ti1[q]; }
        }
    }
    bool ovf = false;
#pragma unroll
    for (int q = 0; q < NTILE; ++q)
        if (tc[q] > 2 && tv1[q] <= v1 + TAU) ovf = true;

    idx_final[m] = i1;
    if (ovf || !(v2 > v1 + TAU)) {
        const int pos = atomicAdd(counter, 1);
        flagged[pos] = m;
        if (ovf) { ncand[m] = 0; }     // sentinel: full-row rescore
        else {
            int k = 0;
            const float thr = v1 + TAU;
#pragma unroll
            for (int q = 0; q < NTILE; ++q) {
                if (tv1[q] <= thr) cand[m * 16 + (k++)] = ti1[q];
                if (tv2[q] <= thr) cand[m * 16 + (k++)] = ti2[q];
            }
            ncand[m] = k;
        }
    }
}

// ---------------------------------------------------------------------------
// Exact fp32 rescore for flagged tokens; candidate dots (wave per candidate),
// full-row fallback when ncand==0. Same (xq - 2g) + cq association.
// ---------------------------------------------------------------------------
__global__ __launch_bounds__(256) void rescore_kernel(
    const float* __restrict__ X, const float* __restrict__ C,
    const float* __restrict__ x_sq, const float* __restrict__ c_sq,
    const int* __restrict__ flagged, const int* __restrict__ counter,
    const int* __restrict__ ncand, const int* __restrict__ cand,
    int* __restrict__ idx_final)
{
    __shared__ __align__(16) float xrow[D_IN];
    __shared__ float bwv[4];
    __shared__ int   bwi[4];
    const int t = threadIdx.x, w = t >> 6, l = t & 63;
    const int nflag = counter[0];

    for (int fi = blockIdx.x; fi < nflag; fi += gridDim.x) {
        const int m = flagged[fi];
        __syncthreads();
        ((float4*)xrow)[t] = ((const float4*)(X + (size_t)m * D_IN))[t];
        __syncthreads();
        const float xq = x_sq[m];
        const int nc = ncand[m];
        float bv = INFINITY; int bi = 0x7fffffff;
        const int lim   = (nc > 0) ? nc : N_CENT;
        for (int ci = w; ci < lim; ci += 4) {
            const int n = (nc > 0) ? cand[m * 16 + ci] : ci;
            const float4* cr = (const float4*)(C + (size_t)n * D_IN);
            float p = 0.f;
#pragma unroll
            for (int k = 0; k < 4; ++k) {
                const float4 cv = cr[l + 64 * k];
                const float4 xv = ((const float4*)xrow)[l + 64 * k];
                p = fmaf(xv.x, cv.x, p); p = fmaf(xv.y, cv.y, p);
                p = fmaf(xv.z, cv.z, p); p = fmaf(xv.w, cv.w, p);
            }
#pragma unroll
            for (int off = 32; off > 0; off >>= 1) p += __shfl_xor(p, off);
            const float d2 = (xq - 2.0f * p) + c_sq[n];
            if (d2 < bv || (d2 == bv && n < bi)) { bv = d2; bi = n; }
        }
        if (l == 0) { bwv[w] = bv; bwi[w] = bi; }
        __syncthreads();
        if (t == 0) {
            float fv = bwv[0]; int fidx = bwi[0];
#pragma unroll
            for (int q = 1; q < 4; ++q)
                if (bwv[q] < fv || (bwv[q] == fv && bwi[q] < fidx)) { fv = bwv[q]; fidx = bwi[q]; }
            idx_final[m] = fidx;
        }
    }
}

// ---------------------------------------------------------------------------
// Final gather + bias. One block per token.
// ---------------------------------------------------------------------------
__global__ __launch_bounds__(256) void gather_kernel(
    const int* __restrict__ idx_final, const float* __restrict__ table,
    const float* __restrict__ bias, float* __restrict__ out)
{
    const int m  = blockIdx.x;
    const int bi = idx_final[m];
    const float4 tv = ((const float4*)(table + (size_t)bi * D_OUT))[threadIdx.x];
    const float4 bv = ((const float4*)bias)[threadIdx.x];
    ((float4*)(out + (size_t)m * D_OUT))[threadIdx.x] =
        make_float4(tv.x + bv.x, tv.y + bv.y, tv.z + bv.z, tv.w + bv.w);
}

// ---------------------------------------------------------------------------
// Launch
// ---------------------------------------------------------------------------
extern "C" void kernel_launch(void* const* d_in, const int* in_sizes, int n_in,
                              void* d_out, int out_size, void* d_ws, size_t ws_size,
                              hipStream_t stream)
{
    const float* X     = (const float*)d_in[0];
    const float* C     = (const float*)d_in[1];
    const float* table = (const float*)d_in[2];
    const float* bias  = (const float*)d_in[3];
    float* out = (float*)d_out;

    char* ws = (char*)d_ws;
    u16*   Xh       = (u16*)(ws);                    // 32 MB
    u16*   Ch       = (u16*)(ws + 33554432);         // 2 MB
    float* x_sq     = (float*)(ws + 35651584);       // 64 KB
    float* c_sq     = (float*)(ws + 35717120);       // 4 KB
    float* pv1      = (float*)(ws + 35721216);       // 512 KB
    int*   pi1      = (int*)(ws + 36245504);         // 512 KB
    float* pv2      = (float*)(ws + 36769792);       // 512 KB
    int*   pi2      = (int*)(ws + 37294080);         // 512 KB
    int*   pcnt     = (int*)(ws + 37818368);         // 512 KB
    int*   idx_fin  = (int*)(ws + 38342656);         // 64 KB
    int*   flagged  = (int*)(ws + 38408192);         // 64 KB
    int*   ncand    = (int*)(ws + 38473728);         // 64 KB
    int*   cand     = (int*)(ws + 38539264);         // 1 MB
    int*   counter  = (int*)(ws + 39587840);         // 4 B

    hipMemsetAsync(counter, 0, 4, stream);

    prep_kernel<<<N_TOK / 4, 256, 0, stream>>>(X, Xh, x_sq, N_TOK);
    prep_kernel<<<N_CENT / 4, 256, 0, stream>>>(C, Ch, c_sq, N_CENT);

    dim3 grid(N_TOK / BM, N_CENT / BN);   // 128 x 8
    gemm_top2_kernel<<<grid, 256, 0, stream>>>(Xh, Ch, x_sq, c_sq,
                                               pv1, pi1, pv2, pi2, pcnt);

    reduce_kernel<<<N_TOK / 256, 256, 0, stream>>>(pv1, pi1, pv2, pi2, pcnt,
                                                   idx_fin, flagged, counter,
                                                   ncand, cand);

    rescore_kernel<<<1024, 256, 0, stream>>>(X, C, x_sq, c_sq, flagged,
                                             counter, ncand, cand, idx_fin);

    gather_kernel<<<N_TOK, 256, 0, stream>>>(idx_fin, table, bias, out);
}

// Round 5
// 349.140 us; speedup vs baseline: 2.2582x; 2.2582x over previous
//
#include <hip/hip_runtime.h>
#include <math.h>

// Problem constants
#define N_TOK  16384   // B*S
#define D_IN   1024
#define D_OUT  1024
#define N_CENT 1024

// GEMM tiling
#define BM 128
#define BN 128
#define BK 64
#define NTILE (N_CENT / BN)   // 8

// Margin: bf16 approx error on d2 max ~1.6e-2 over all pairs; TAU >= 2*maxerr
// guarantees (a) unique-gap argmin exact, (b) candidate set {d2a <= gmin+TAU}
// contains the exact argmin. TAU=0.05 passed R3/R4 with absmax 0.
#define TAU 0.05f

typedef __attribute__((ext_vector_type(8))) short short8;
typedef __attribute__((ext_vector_type(4))) float float4v;
typedef unsigned int u32;
typedef unsigned short u16;

__device__ __forceinline__ void async_copy16(const void* g, void* l) {
    __builtin_amdgcn_global_load_lds(
        (const __attribute__((address_space(1))) u32*)g,
        (__attribute__((address_space(3))) u32*)l, 16, 0, 0);
}

__device__ __forceinline__ u16 f32_to_bf16_rne(float f) {
    u32 u = __float_as_uint(f);
    u32 r = (u + 0x7FFFu + ((u >> 16) & 1u)) >> 16;
    return (u16)r;
}

// Merge two ascending-sorted top-3 lists (lex on (val,idx) for ranks 1-2,
// value-only for rank 3) into a's registers.
__device__ __forceinline__ void merge3(
    float& a1, int& ai1, float& a2, int& ai2, float& a3,
    float b1, int bi1, float b2, int bi2, float b3)
{
    float o1, o2, o3; int o1i, o2i;
    const bool bwin1 = (b1 < a1) || (b1 == a1 && bi1 < ai1);
    if (!bwin1) {
        o1 = a1; o1i = ai1;
        const bool bwin2 = (b1 < a2) || (b1 == a2 && bi1 < ai2);
        if (!bwin2) { o2 = a2; o2i = ai2; o3 = fminf(a3, b1); }
        else        { o2 = b1; o2i = bi1; o3 = fminf(a2, b2); }
    } else {
        o1 = b1; o1i = bi1;
        const bool awin2 = (a1 < b2) || (a1 == b2 && ai1 < bi2);
        if (awin2) { o2 = a1; o2i = ai1; o3 = fminf(a2, b2); }
        else       { o2 = b2; o2i = bi2; o3 = fminf(a1, b3); }
    }
    a1 = o1; ai1 = o1i; a2 = o2; ai2 = o2i; a3 = o3;
}

// ---------------------------------------------------------------------------
// Fused fp32->bf16 convert + row squared norm for BOTH X and C (one launch).
// One wave per row; identical arithmetic to the R3/R4-validated version.
// ---------------------------------------------------------------------------
__global__ __launch_bounds__(256) void prep_kernel(
    const float* __restrict__ X, const float* __restrict__ C,
    u16* __restrict__ Xh, u16* __restrict__ Ch,
    float* __restrict__ xsq, float* __restrict__ csq)
{
    const int wv = threadIdx.x >> 6;
    const int l  = threadIdx.x & 63;
    int row = blockIdx.x * 4 + wv;
    const float* src; u16* dsth; float* dsts;
    if (row < N_TOK) { src = X; dsth = Xh; dsts = xsq; }
    else { row -= N_TOK; src = C; dsth = Ch; dsts = csq; }
    const float4* xr = (const float4*)(src + (size_t)row * D_IN);
    ushort4* hr = (ushort4*)(dsth + (size_t)row * D_IN);
    float s = 0.f;
#pragma unroll
    for (int i = 0; i < 4; ++i) {
        float4 v = xr[l + i * 64];
        ushort4 o;
        o.x = f32_to_bf16_rne(v.x); o.y = f32_to_bf16_rne(v.y);
        o.z = f32_to_bf16_rne(v.z); o.w = f32_to_bf16_rne(v.w);
        hr[l + i * 64] = o;
        s += v.x * v.x + v.y * v.y + v.z * v.z + v.w * v.w;
    }
#pragma unroll
    for (int off = 32; off > 0; off >>= 1) s += __shfl_down(s, off);
    if (l == 0) dsts[row] = s;
}

// ---------------------------------------------------------------------------
// bf16 MFMA GEMM with fused per-tile TOP-3 argmin epilogue.
// 256 threads = 4 waves (2x2); wave = 64x64 subtile = 4x4 of 16x16x32 MFMA.
// LDS: 8-octet rows (128 B), octet XOR swizzle by (row&7).
// Emits per (token, n-tile): top-2 (val,idx) lex + v3 value. SoA [tile][tok].
// ---------------------------------------------------------------------------
__global__ __launch_bounds__(256, 4) void gemm_top3_kernel(
    const u16* __restrict__ Xh, const u16* __restrict__ Ch,
    const float* __restrict__ x_sq, const float* __restrict__ c_sq,
    float* __restrict__ pv1, int* __restrict__ pi1,
    float* __restrict__ pv2, int* __restrict__ pi2,
    float* __restrict__ pv3)
{
    __shared__ __align__(16) u16 As[BM * BK];   // 16 KB
    __shared__ __align__(16) u16 Bs[BN * BK];   // 16 KB

    const int t  = threadIdx.x;
    const int w  = t >> 6;
    const int l  = t & 63;
    const int wi = w >> 1, wj = w & 1;
    const int m0 = blockIdx.x * BM;
    const int n0 = blockIdx.y * BN;
    const int quad = l >> 4;
    const int r15  = l & 15;

    float4v acc[4][4];
#pragma unroll
    for (int i = 0; i < 4; ++i)
#pragma unroll
        for (int j = 0; j < 4; ++j)
            acc[i][j] = (float4v){0.f, 0.f, 0.f, 0.f};

    for (int k0 = 0; k0 < D_IN; k0 += BK) {
#pragma unroll
        for (int r = 0; r < 4; ++r) {
            const int s   = r * 256 + t;
            const int row = s >> 3;
            const int q   = (s & 7) ^ (row & 7);
            async_copy16(Xh + (size_t)(m0 + row) * D_IN + k0 + q * 8, As + s * 8);
            async_copy16(Ch + (size_t)(n0 + row) * D_IN + k0 + q * 8, Bs + s * 8);
        }
        __syncthreads();
#pragma unroll
        for (int kk2 = 0; kk2 < 2; ++kk2) {
            short8 af[4], bfr[4];
#pragma unroll
            for (int i = 0; i < 4; ++i) {
                const int r = wi * 64 + i * 16 + r15;
                af[i] = *(const short8*)(As + (r * 8 + ((kk2 * 4 + quad) ^ (r & 7))) * 8);
            }
#pragma unroll
            for (int j = 0; j < 4; ++j) {
                const int r = wj * 64 + j * 16 + r15;
                bfr[j] = *(const short8*)(Bs + (r * 8 + ((kk2 * 4 + quad) ^ (r & 7))) * 8);
            }
#pragma unroll
            for (int i = 0; i < 4; ++i)
#pragma unroll
                for (int j = 0; j < 4; ++j)
                    acc[i][j] = __builtin_amdgcn_mfma_f32_16x16x32_bf16(
                        af[i], bfr[j], acc[i][j], 0, 0, 0);
        }
        __syncthreads();
    }

    // Epilogue arena reuses As: [BM][2] x {v1,i1,v2,i2,v3} = 5 KB.
    float* rv1 = (float*)As;
    int*   ri1 = (int*)(rv1 + 256);
    float* rv2 = (float*)(ri1 + 256);
    int*   ri2 = (int*)(rv2 + 256);
    float* rv3 = (float*)(ri2 + 256);

    const int nbase = n0 + wj * 64 + r15;
    float cq[4];
#pragma unroll
    for (int j = 0; j < 4; ++j) cq[j] = c_sq[nbase + j * 16];

#pragma unroll
    for (int i = 0; i < 4; ++i) {
#pragma unroll
        for (int reg = 0; reg < 4; ++reg) {
            const int rloc = wi * 64 + i * 16 + quad * 4 + reg;
            const float xq = x_sq[m0 + rloc];
            float d[4];
#pragma unroll
            for (int j = 0; j < 4; ++j)
                d[j] = (xq - 2.0f * acc[i][j][reg]) + cq[j];
            // thread-local top-3 (ascending n + strict < => lex-sorted)
            float v1 = d[0], v2 = INFINITY, v3 = INFINITY;
            int   i1 = nbase, i2 = 0x7fffffff;
#pragma unroll
            for (int j = 1; j < 4; ++j) {
                const int n = nbase + j * 16;
                if (d[j] < v1)      { v3 = v2; v2 = v1; i2 = i1; v1 = d[j]; i1 = n; }
                else if (d[j] < v2) { v3 = v2; v2 = d[j]; i2 = n; }
                else if (d[j] < v3) { v3 = d[j]; }
            }
            // 16-lane butterfly top-3 merge (stays within the quad group)
#pragma unroll
            for (int off = 1; off < 16; off <<= 1) {
                const float b1 = __shfl_xor(v1, off); const int j1 = __shfl_xor(i1, off);
                const float b2 = __shfl_xor(v2, off); const int j2 = __shfl_xor(i2, off);
                const float b3 = __shfl_xor(v3, off);
                merge3(v1, i1, v2, i2, v3, b1, j1, b2, j2, b3);
            }
            if (r15 == 0) {
                rv1[rloc * 2 + wj] = v1; ri1[rloc * 2 + wj] = i1;
                rv2[rloc * 2 + wj] = v2; ri2[rloc * 2 + wj] = i2;
                rv3[rloc * 2 + wj] = v3;
            }
        }
    }
    __syncthreads();
    if (t < BM) {
        float a1 = rv1[t * 2], a2 = rv2[t * 2], a3 = rv3[t * 2];
        int   x1 = ri1[t * 2], x2 = ri2[t * 2];
        merge3(a1, x1, a2, x2, a3,
               rv1[t * 2 + 1], ri1[t * 2 + 1],
               rv2[t * 2 + 1], ri2[t * 2 + 1], rv3[t * 2 + 1]);
        const size_t o = (size_t)blockIdx.y * N_TOK + m0 + t;
        pv1[o] = a1; pi1[o] = x1; pv2[o] = a2; pi2[o] = x2; pv3[o] = a3;
    }
}

// ---------------------------------------------------------------------------
// Per-token merge of NTILE tile top-3s. Candidate-set completeness is exact:
// the tile top-2 union covers everything <= gmin+TAU iff no tile v3 <= thr.
// ---------------------------------------------------------------------------
__global__ __launch_bounds__(256) void reduce_kernel(
    const float* __restrict__ pv1, const int* __restrict__ pi1,
    const float* __restrict__ pv2, const int* __restrict__ pi2,
    const float* __restrict__ pv3,
    int* __restrict__ idx_final, int* __restrict__ flagged,
    int* __restrict__ counter, int* __restrict__ ncand, int* __restrict__ cand)
{
    const int m = blockIdx.x * 256 + threadIdx.x;
    float tv1[NTILE], tv2[NTILE], tv3[NTILE];
    int   ti1[NTILE], ti2[NTILE];
    float v1 = INFINITY, v2 = INFINITY;
    int   i1 = 0x7fffffff, i2 = 0x7fffffff;
#pragma unroll
    for (int q = 0; q < NTILE; ++q) {
        tv1[q] = pv1[q * N_TOK + m]; ti1[q] = pi1[q * N_TOK + m];
        tv2[q] = pv2[q * N_TOK + m]; ti2[q] = pi2[q * N_TOK + m];
        tv3[q] = pv3[q * N_TOK + m];
        if (tv1[q] < v1 || (tv1[q] == v1 && ti1[q] < i1)) {
            if (v1 < tv2[q] || (v1 == tv2[q] && i1 < ti2[q])) { v2 = v1; i2 = i1; }
            else { v2 = tv2[q]; i2 = ti2[q]; }
            v1 = tv1[q]; i1 = ti1[q];
        } else {
            if (tv1[q] < v2 || (tv1[q] == v2 && ti1[q] < i2)) { v2 = tv1[q]; i2 = ti1[q]; }
        }
    }
    const float thr = v1 + TAU;
    bool ovf = false;
#pragma unroll
    for (int q = 0; q < NTILE; ++q)
        if (tv3[q] <= thr) ovf = true;

    idx_final[m] = i1;
    if (ovf || v2 <= thr) {
        const int pos = atomicAdd(counter, 1);
        flagged[pos] = m;
        if (ovf) { ncand[m] = 0; }     // sentinel: full-row rescore (rare)
        else {
            int k = 0;
#pragma unroll
            for (int q = 0; q < NTILE; ++q) {
                if (tv1[q] <= thr) cand[m * 16 + (k++)] = ti1[q];
                if (tv2[q] <= thr) cand[m * 16 + (k++)] = ti2[q];
            }
            ncand[m] = k;
        }
    }
}

// ---------------------------------------------------------------------------
// Exact fp32 rescore for flagged tokens (same association as reference).
// ---------------------------------------------------------------------------
__global__ __launch_bounds__(256) void rescore_kernel(
    const float* __restrict__ X, const float* __restrict__ C,
    const float* __restrict__ x_sq, const float* __restrict__ c_sq,
    const int* __restrict__ flagged, const int* __restrict__ counter,
    const int* __restrict__ ncand, const int* __restrict__ cand,
    int* __restrict__ idx_final)
{
    __shared__ __align__(16) float xrow[D_IN];
    __shared__ float bwv[4];
    __shared__ int   bwi[4];
    const int t = threadIdx.x, w = t >> 6, l = t & 63;
    const int nflag = counter[0];

    for (int fi = blockIdx.x; fi < nflag; fi += gridDim.x) {
        const int m = flagged[fi];
        __syncthreads();
        ((float4*)xrow)[t] = ((const float4*)(X + (size_t)m * D_IN))[t];
        __syncthreads();
        const float xq = x_sq[m];
        const int nc = ncand[m];
        float bv = INFINITY; int bi = 0x7fffffff;
        const int lim = (nc > 0) ? nc : N_CENT;
        for (int ci = w; ci < lim; ci += 4) {
            const int n = (nc > 0) ? cand[m * 16 + ci] : ci;
            const float4* cr = (const float4*)(C + (size_t)n * D_IN);
            float p = 0.f;
#pragma unroll
            for (int k = 0; k < 4; ++k) {
                const float4 cv = cr[l + 64 * k];
                const float4 xv = ((const float4*)xrow)[l + 64 * k];
                p = fmaf(xv.x, cv.x, p); p = fmaf(xv.y, cv.y, p);
                p = fmaf(xv.z, cv.z, p); p = fmaf(xv.w, cv.w, p);
            }
#pragma unroll
            for (int off = 32; off > 0; off >>= 1) p += __shfl_xor(p, off);
            const float d2 = (xq - 2.0f * p) + c_sq[n];
            if (d2 < bv || (d2 == bv && n < bi)) { bv = d2; bi = n; }
        }
        if (l == 0) { bwv[w] = bv; bwi[w] = bi; }
        __syncthreads();
        if (t == 0) {
            float fv = bwv[0]; int fidx = bwi[0];
#pragma unroll
            for (int q = 1; q < 4; ++q)
                if (bwv[q] < fv || (bwv[q] == fv && bwi[q] < fidx)) { fv = bwv[q]; fidx = bwi[q]; }
            idx_final[m] = fidx;
        }
    }
}

// ---------------------------------------------------------------------------
// Final gather + bias. One block per token.
// ---------------------------------------------------------------------------
__global__ __launch_bounds__(256) void gather_kernel(
    const int* __restrict__ idx_final, const float* __restrict__ table,
    const float* __restrict__ bias, float* __restrict__ out)
{
    const int m  = blockIdx.x;
    const int bi = idx_final[m];
    const float4 tv = ((const float4*)(table + (size_t)bi * D_OUT))[threadIdx.x];
    const float4 bv = ((const float4*)bias)[threadIdx.x];
    ((float4*)(out + (size_t)m * D_OUT))[threadIdx.x] =
        make_float4(tv.x + bv.x, tv.y + bv.y, tv.z + bv.z, tv.w + bv.w);
}

// ---------------------------------------------------------------------------
// Launch
// ---------------------------------------------------------------------------
extern "C" void kernel_launch(void* const* d_in, const int* in_sizes, int n_in,
                              void* d_out, int out_size, void* d_ws, size_t ws_size,
                              hipStream_t stream)
{
    const float* X     = (const float*)d_in[0];
    const float* C     = (const float*)d_in[1];
    const float* table = (const float*)d_in[2];
    const float* bias  = (const float*)d_in[3];
    float* out = (float*)d_out;

    char* ws = (char*)d_ws;
    u16*   Xh       = (u16*)(ws);                    // 32 MB
    u16*   Ch       = (u16*)(ws + 33554432);         // 2 MB
    float* x_sq     = (float*)(ws + 35651584);       // 64 KB
    float* c_sq     = (float*)(ws + 35717120);       // 4 KB
    float* pv1      = (float*)(ws + 35721216);       // 512 KB
    int*   pi1      = (int*)(ws + 36245504);         // 512 KB
    float* pv2      = (float*)(ws + 36769792);       // 512 KB
    int*   pi2      = (int*)(ws + 37294080);         // 512 KB
    float* pv3      = (float*)(ws + 37818368);       // 512 KB
    int*   idx_fin  = (int*)(ws + 38342656);         // 64 KB
    int*   flagged  = (int*)(ws + 38408192);         // 64 KB
    int*   ncand    = (int*)(ws + 38473728);         // 64 KB
    int*   cand     = (int*)(ws + 38539264);         // 1 MB
    int*   counter  = (int*)(ws + 39587840);         // 4 B

    hipMemsetAsync(counter, 0, 4, stream);

    prep_kernel<<<(N_TOK + N_CENT) / 4, 256, 0, stream>>>(X, C, Xh, Ch, x_sq, c_sq);

    dim3 grid(N_TOK / BM, N_CENT / BN);   // 128 x 8
    gemm_top3_kernel<<<grid, 256, 0, stream>>>(Xh, Ch, x_sq, c_sq,
                                               pv1, pi1, pv2, pi2, pv3);

    reduce_kernel<<<N_TOK / 256, 256, 0, stream>>>(pv1, pi1, pv2, pi2, pv3,
                                                   idx_fin, flagged, counter,
                                                   ncand, cand);

    rescore_kernel<<<1024, 256, 0, stream>>>(X, C, x_sq, c_sq, flagged,
                                             counter, ncand, cand, idx_fin);

    gather_kernel<<<N_TOK, 256, 0, stream>>>(idx_fin, table, bias, out);
}

// Round 7
// 231.007 us; speedup vs baseline: 3.4130x; 1.5114x over previous
//
#include <hip/hip_runtime.h>
#include <math.h>

// Problem constants
#define N_TOK  16384   // B*S
#define D_IN   1024
#define D_OUT  1024
#define N_CENT 1024

// GEMM tiling
#define BM 128
#define BN 128
#define BK 64
#define NTILE (N_CENT / BN)   // 8

// Margin: bf16 approx error on d2 max ~1.6e-2 over all pairs; TAU >= 2*maxerr
// guarantees (a) unique-gap argmin exact, (b) candidate set {d2a <= gmin+TAU}
// contains the exact argmin. TAU=0.05 validated R3/R4/R5 (absmax 0).
#define TAU 0.05f

#define SENT 0xFFFFFFFFFFFFFFFFull

typedef __attribute__((ext_vector_type(8))) short short8;
typedef __attribute__((ext_vector_type(4))) float float4v;
typedef unsigned int u32;
typedef unsigned short u16;
typedef unsigned long long u64;

__device__ __forceinline__ void async_copy16(const void* g, void* l) {
    __builtin_amdgcn_global_load_lds(
        (const __attribute__((address_space(1))) u32*)g,
        (__attribute__((address_space(3))) u32*)l, 16, 0, 0);
}

__device__ __forceinline__ u16 f32_to_bf16_rne(float f) {
    u32 u = __float_as_uint(f);
    u32 r = (u + 0x7FFFu + ((u >> 16) & 1u)) >> 16;
    return (u16)r;
}

// Merge two ascending-sorted top-3 lists (lex on (val,idx) for ranks 1-2,
// value-only for rank 3) into a's registers.  (R5-validated)
__device__ __forceinline__ void merge3(
    float& a1, int& ai1, float& a2, int& ai2, float& a3,
    float b1, int bi1, float b2, int bi2, float b3)
{
    float o1, o2, o3; int o1i, o2i;
    const bool bwin1 = (b1 < a1) || (b1 == a1 && bi1 < ai1);
    if (!bwin1) {
        o1 = a1; o1i = ai1;
        const bool bwin2 = (b1 < a2) || (b1 == a2 && bi1 < ai2);
        if (!bwin2) { o2 = a2; o2i = ai2; o3 = fminf(a3, b1); }
        else        { o2 = b1; o2i = bi1; o3 = fminf(a2, b2); }
    } else {
        o1 = b1; o1i = bi1;
        const bool awin2 = (a1 < b2) || (a1 == b2 && ai1 < bi2);
        if (awin2) { o2 = a1; o2i = ai1; o3 = fminf(a2, b2); }
        else       { o2 = b2; o2i = bi2; o3 = fminf(a1, b3); }
    }
    a1 = o1; ai1 = o1i; a2 = o2; ai2 = o2i; a3 = o3;
}

// Wave dot product of row m of X and row n of C; identical summation order
// to the R5-validated rescore (bit-exact across both rescore kernels).
__device__ __forceinline__ float wave_dot(
    const float* __restrict__ X, const float* __restrict__ C,
    int m, int n, int l)
{
    const float4* xr = (const float4*)(X + (size_t)m * D_IN);
    const float4* cr = (const float4*)(C + (size_t)n * D_IN);
    float p = 0.f;
#pragma unroll
    for (int k = 0; k < 4; ++k) {
        const float4 cv = cr[l + 64 * k];
        const float4 xv = xr[l + 64 * k];
        p = fmaf(xv.x, cv.x, p); p = fmaf(xv.y, cv.y, p);
        p = fmaf(xv.z, cv.z, p); p = fmaf(xv.w, cv.w, p);
    }
#pragma unroll
    for (int off = 32; off > 0; off >>= 1) p += __shfl_xor(p, off);
    return p;
}

// ---------------------------------------------------------------------------
// Fused fp32->bf16 convert + row squared norm for BOTH X and C.
// ---------------------------------------------------------------------------
__global__ __launch_bounds__(256) void prep_kernel(
    const float* __restrict__ X, const float* __restrict__ C,
    u16* __restrict__ Xh, u16* __restrict__ Ch,
    float* __restrict__ xsq, float* __restrict__ csq)
{
    const int wv = threadIdx.x >> 6;
    const int l  = threadIdx.x & 63;
    int row = blockIdx.x * 4 + wv;
    const float* src; u16* dsth; float* dsts;
    if (row < N_TOK) { src = X; dsth = Xh; dsts = xsq; }
    else { row -= N_TOK; src = C; dsth = Ch; dsts = csq; }
    const float4* xr = (const float4*)(src + (size_t)row * D_IN);
    ushort4* hr = (ushort4*)(dsth + (size_t)row * D_IN);
    float s = 0.f;
#pragma unroll
    for (int i = 0; i < 4; ++i) {
        float4 v = xr[l + i * 64];
        ushort4 o;
        o.x = f32_to_bf16_rne(v.x); o.y = f32_to_bf16_rne(v.y);
        o.z = f32_to_bf16_rne(v.z); o.w = f32_to_bf16_rne(v.w);
        hr[l + i * 64] = o;
        s += v.x * v.x + v.y * v.y + v.z * v.z + v.w * v.w;
    }
#pragma unroll
    for (int off = 32; off > 0; off >>= 1) s += __shfl_down(s, off);
    if (l == 0) dsts[row] = s;
}

// ---------------------------------------------------------------------------
// bf16 MFMA GEMM with fused per-tile TOP-3 argmin epilogue. (R5-validated)
// ---------------------------------------------------------------------------
__global__ __launch_bounds__(256, 4) void gemm_top3_kernel(
    const u16* __restrict__ Xh, const u16* __restrict__ Ch,
    const float* __restrict__ x_sq, const float* __restrict__ c_sq,
    float* __restrict__ pv1, int* __restrict__ pi1,
    float* __restrict__ pv2, int* __restrict__ pi2,
    float* __restrict__ pv3)
{
    __shared__ __align__(16) u16 As[BM * BK];   // 16 KB
    __shared__ __align__(16) u16 Bs[BN * BK];   // 16 KB

    const int t  = threadIdx.x;
    const int w  = t >> 6;
    const int l  = t & 63;
    const int wi = w >> 1, wj = w & 1;
    const int m0 = blockIdx.x * BM;
    const int n0 = blockIdx.y * BN;
    const int quad = l >> 4;
    const int r15  = l & 15;

    float4v acc[4][4];
#pragma unroll
    for (int i = 0; i < 4; ++i)
#pragma unroll
        for (int j = 0; j < 4; ++j)
            acc[i][j] = (float4v){0.f, 0.f, 0.f, 0.f};

    for (int k0 = 0; k0 < D_IN; k0 += BK) {
#pragma unroll
        for (int r = 0; r < 4; ++r) {
            const int s   = r * 256 + t;
            const int row = s >> 3;
            const int q   = (s & 7) ^ (row & 7);
            async_copy16(Xh + (size_t)(m0 + row) * D_IN + k0 + q * 8, As + s * 8);
            async_copy16(Ch + (size_t)(n0 + row) * D_IN + k0 + q * 8, Bs + s * 8);
        }
        __syncthreads();
#pragma unroll
        for (int kk2 = 0; kk2 < 2; ++kk2) {
            short8 af[4], bfr[4];
#pragma unroll
            for (int i = 0; i < 4; ++i) {
                const int r = wi * 64 + i * 16 + r15;
                af[i] = *(const short8*)(As + (r * 8 + ((kk2 * 4 + quad) ^ (r & 7))) * 8);
            }
#pragma unroll
            for (int j = 0; j < 4; ++j) {
                const int r = wj * 64 + j * 16 + r15;
                bfr[j] = *(const short8*)(Bs + (r * 8 + ((kk2 * 4 + quad) ^ (r & 7))) * 8);
            }
#pragma unroll
            for (int i = 0; i < 4; ++i)
#pragma unroll
                for (int j = 0; j < 4; ++j)
                    acc[i][j] = __builtin_amdgcn_mfma_f32_16x16x32_bf16(
                        af[i], bfr[j], acc[i][j], 0, 0, 0);
        }
        __syncthreads();
    }

    float* rv1 = (float*)As;
    int*   ri1 = (int*)(rv1 + 256);
    float* rv2 = (float*)(ri1 + 256);
    int*   ri2 = (int*)(rv2 + 256);
    float* rv3 = (float*)(ri2 + 256);

    const int nbase = n0 + wj * 64 + r15;
    float cq[4];
#pragma unroll
    for (int j = 0; j < 4; ++j) cq[j] = c_sq[nbase + j * 16];

#pragma unroll
    for (int i = 0; i < 4; ++i) {
#pragma unroll
        for (int reg = 0; reg < 4; ++reg) {
            const int rloc = wi * 64 + i * 16 + quad * 4 + reg;
            const float xq = x_sq[m0 + rloc];
            float d[4];
#pragma unroll
            for (int j = 0; j < 4; ++j)
                d[j] = (xq - 2.0f * acc[i][j][reg]) + cq[j];
            float v1 = d[0], v2 = INFINITY, v3 = INFINITY;
            int   i1 = nbase, i2 = 0x7fffffff;
#pragma unroll
            for (int j = 1; j < 4; ++j) {
                const int n = nbase + j * 16;
                if (d[j] < v1)      { v3 = v2; v2 = v1; i2 = i1; v1 = d[j]; i1 = n; }
                else if (d[j] < v2) { v3 = v2; v2 = d[j]; i2 = n; }
                else if (d[j] < v3) { v3 = d[j]; }
            }
#pragma unroll
            for (int off = 1; off < 16; off <<= 1) {
                const float b1 = __shfl_xor(v1, off); const int j1 = __shfl_xor(i1, off);
                const float b2 = __shfl_xor(v2, off); const int j2 = __shfl_xor(i2, off);
                const float b3 = __shfl_xor(v3, off);
                merge3(v1, i1, v2, i2, v3, b1, j1, b2, j2, b3);
            }
            if (r15 == 0) {
                rv1[rloc * 2 + wj] = v1; ri1[rloc * 2 + wj] = i1;
                rv2[rloc * 2 + wj] = v2; ri2[rloc * 2 + wj] = i2;
                rv3[rloc * 2 + wj] = v3;
            }
        }
    }
    __syncthreads();
    if (t < BM) {
        float a1 = rv1[t * 2], a2 = rv2[t * 2], a3 = rv3[t * 2];
        int   x1 = ri1[t * 2], x2 = ri2[t * 2];
        merge3(a1, x1, a2, x2, a3,
               rv1[t * 2 + 1], ri1[t * 2 + 1],
               rv2[t * 2 + 1], ri2[t * 2 + 1], rv3[t * 2 + 1]);
        const size_t o = (size_t)blockIdx.y * N_TOK + m0 + t;
        pv1[o] = a1; pi1[o] = x1; pv2[o] = a2; pi2[o] = x2; pv3[o] = a3;
    }
}

// ---------------------------------------------------------------------------
// Per-token merge of NTILE tile top-3s. Builds:
//  - bounded candidate work list (<= 16 items/token, capacity 16384*16), and
//  - ovf_list of tokens needing full-row rescore (capacity 16384).
// Completeness exact: tile top-2 union covers everything <= gmin+TAU iff no
// tile v3 <= thr.
// ---------------------------------------------------------------------------
__global__ __launch_bounds__(256) void reduce_kernel(
    const float* __restrict__ pv1, const int* __restrict__ pi1,
    const float* __restrict__ pv2, const int* __restrict__ pi2,
    const float* __restrict__ pv3,
    int* __restrict__ idx_final, u64* __restrict__ packed,
    int* __restrict__ wcount, u32* __restrict__ work,
    int* __restrict__ ovfcount, int* __restrict__ ovf_list)
{
    const int m = blockIdx.x * 256 + threadIdx.x;
    float tv1[NTILE], tv2[NTILE], tv3[NTILE];
    int   ti1[NTILE], ti2[NTILE];
    float v1 = INFINITY, v2 = INFINITY;
    int   i1 = 0x7fffffff, i2 = 0x7fffffff;
#pragma unroll
    for (int q = 0; q < NTILE; ++q) {
        tv1[q] = pv1[q * N_TOK + m]; ti1[q] = pi1[q * N_TOK + m];
        tv2[q] = pv2[q * N_TOK + m]; ti2[q] = pi2[q * N_TOK + m];
        tv3[q] = pv3[q * N_TOK + m];
        if (tv1[q] < v1 || (tv1[q] == v1 && ti1[q] < i1)) {
            if (v1 < tv2[q] || (v1 == tv2[q] && i1 < ti2[q])) { v2 = v1; i2 = i1; }
            else { v2 = tv2[q]; i2 = ti2[q]; }
            v1 = tv1[q]; i1 = ti1[q];
        } else {
            if (tv1[q] < v2 || (tv1[q] == v2 && ti1[q] < i2)) { v2 = tv1[q]; i2 = ti1[q]; }
        }
    }
    const float thr = v1 + TAU;
    bool ovf = false;
#pragma unroll
    for (int q = 0; q < NTILE; ++q)
        if (tv3[q] <= thr) ovf = true;

    idx_final[m] = i1;
    packed[m] = SENT;
    if (ovf) {
        const int pos = atomicAdd(ovfcount, 1);
        ovf_list[pos] = m;
    } else if (v2 <= thr) {
        int k = 0; int cd[2 * NTILE];
#pragma unroll
        for (int q = 0; q < NTILE; ++q) {
            if (tv1[q] <= thr) cd[k++] = ti1[q];
            if (tv2[q] <= thr) cd[k++] = ti2[q];
        }
        const int base = atomicAdd(wcount, k);
        for (int i = 0; i < k; ++i)
            work[base + i] = ((u32)m << 10) | (u32)cd[i];
    }
}

// ---------------------------------------------------------------------------
// Exact fp32 rescore, candidate list: ONE WAVE PER work item, grid-stride.
// Result via u64 atomicMin on (d2_bits<<32 | n): d2 ~ 1e3 > 0 so float bits
// are order-monotone; lex (val,idx) == numpy first-occurrence tie-break.
// ---------------------------------------------------------------------------
__global__ __launch_bounds__(256) void rescore_cand_kernel(
    const float* __restrict__ X, const float* __restrict__ C,
    const float* __restrict__ x_sq, const float* __restrict__ c_sq,
    const u32* __restrict__ work, const int* __restrict__ wcount,
    u64* __restrict__ packed)
{
    const int l = threadIdx.x & 63;
    const int nw = wcount[0];
    const int wgid   = blockIdx.x * 4 + (threadIdx.x >> 6);
    const int nwaves = gridDim.x * 4;

    for (int i = wgid; i < nw; i += nwaves) {
        const u32 item = work[i];
        const int m = (int)(item >> 10);
        const int n = (int)(item & 1023u);
        const float p = wave_dot(X, C, m, n, l);
        if (l == 0) {
            const float d2 = (x_sq[m] - 2.0f * p) + c_sq[n];
            const u64 pk = ((u64)__float_as_uint(d2) << 32) | (u32)n;
            atomicMin(&packed[m], pk);
        }
    }
}

// ---------------------------------------------------------------------------
// Exact fp32 rescore, ovf tokens: ONE WAVE PER (ovf token, centroid),
// grid-stride over ovfcount*1024 flat items. Fully parallel -- no serial tail.
// ---------------------------------------------------------------------------
__global__ __launch_bounds__(256) void rescore_ovf_kernel(
    const float* __restrict__ X, const float* __restrict__ C,
    const float* __restrict__ x_sq, const float* __restrict__ c_sq,
    const int* __restrict__ ovf_list, const int* __restrict__ ovfcount,
    u64* __restrict__ packed)
{
    const int l = threadIdx.x & 63;
    const int nitems = ovfcount[0] * N_CENT;
    const int wgid   = blockIdx.x * 4 + (threadIdx.x >> 6);
    const int nwaves = gridDim.x * 4;

    for (int i = wgid; i < nitems; i += nwaves) {
        const int m = ovf_list[i >> 10];
        const int n = i & 1023;
        const float p = wave_dot(X, C, m, n, l);
        if (l == 0) {
            const float d2 = (x_sq[m] - 2.0f * p) + c_sq[n];
            const u64 pk = ((u64)__float_as_uint(d2) << 32) | (u32)n;
            atomicMin(&packed[m], pk);
        }
    }
}

// ---------------------------------------------------------------------------
// Writeback: any token whose packed slot was written takes its exact argmin.
// ---------------------------------------------------------------------------
__global__ __launch_bounds__(256) void writeback_kernel(
    const u64* __restrict__ packed, int* __restrict__ idx_final)
{
    const int m = blockIdx.x * 256 + threadIdx.x;
    const u64 pk = packed[m];
    if (pk != SENT) idx_final[m] = (int)(pk & 1023u);
}

// ---------------------------------------------------------------------------
// Final gather + bias. One block per token.
// ---------------------------------------------------------------------------
__global__ __launch_bounds__(256) void gather_kernel(
    const int* __restrict__ idx_final, const float* __restrict__ table,
    const float* __restrict__ bias, float* __restrict__ out)
{
    const int m  = blockIdx.x;
    const int bi = idx_final[m];
    const float4 tv = ((const float4*)(table + (size_t)bi * D_OUT))[threadIdx.x];
    const float4 bv = ((const float4*)bias)[threadIdx.x];
    ((float4*)(out + (size_t)m * D_OUT))[threadIdx.x] =
        make_float4(tv.x + bv.x, tv.y + bv.y, tv.z + bv.z, tv.w + bv.w);
}

// ---------------------------------------------------------------------------
// Launch.  Workspace map (byte offsets, all extents padded & verified):
//   Xh      0          32 MiB   (16384*1024*2 = 33,554,432)
//   Ch      33,554,432  2 MiB   (1024*1024*2  =  2,097,152)
//   x_sq    35,651,584  64 KiB
//   c_sq    35,717,120  4 KiB
//   pv1     35,721,216  512 KiB (8*16384*4 = 524,288)
//   pi1     36,245,504  512 KiB
//   pv2     36,769,792  512 KiB
//   pi2     37,294,080  512 KiB
//   pv3     37,818,368  512 KiB
//   idx_fin 38,342,656  64 KiB
//   packed  38,408,192  128 KiB (16384*8 = 131,072)  ends 38,539,264
//   work    38,539,264  1 MiB   (16384*16*4 = 1,048,576 -- exact worst case)
//   ovf     39,587,840  64 KiB  (16384*4)
//   ctrs    39,653,376  256 B   (wcount @ +0, ovfcount @ +4)
//   total   39,653,632  (~37.8 MiB; R3 proved ws_size >= ~98 MiB)
// ---------------------------------------------------------------------------
extern "C" void kernel_launch(void* const* d_in, const int* in_sizes, int n_in,
                              void* d_out, int out_size, void* d_ws, size_t ws_size,
                              hipStream_t stream)
{
    const float* X     = (const float*)d_in[0];
    const float* C     = (const float*)d_in[1];
    const float* table = (const float*)d_in[2];
    const float* bias  = (const float*)d_in[3];
    float* out = (float*)d_out;

    char* ws = (char*)d_ws;
    u16*   Xh       = (u16*)(ws);
    u16*   Ch       = (u16*)(ws + 33554432);
    float* x_sq     = (float*)(ws + 35651584);
    float* c_sq     = (float*)(ws + 35717120);
    float* pv1      = (float*)(ws + 35721216);
    int*   pi1      = (int*)(ws + 36245504);
    float* pv2      = (float*)(ws + 36769792);
    int*   pi2      = (int*)(ws + 37294080);
    float* pv3      = (float*)(ws + 37818368);
    int*   idx_fin  = (int*)(ws + 38342656);
    u64*   packed   = (u64*)(ws + 38408192);
    u32*   work     = (u32*)(ws + 38539264);
    int*   ovf_list = (int*)(ws + 39587840);
    int*   wcount   = (int*)(ws + 39653376);
    int*   ovfcount = (int*)(ws + 39653380);

    hipMemsetAsync(wcount, 0, 8, stream);            // wcount + ovfcount

    prep_kernel<<<(N_TOK + N_CENT) / 4, 256, 0, stream>>>(X, C, Xh, Ch, x_sq, c_sq);

    dim3 grid(N_TOK / BM, N_CENT / BN);   // 128 x 8
    gemm_top3_kernel<<<grid, 256, 0, stream>>>(Xh, Ch, x_sq, c_sq,
                                               pv1, pi1, pv2, pi2, pv3);

    reduce_kernel<<<N_TOK / 256, 256, 0, stream>>>(pv1, pi1, pv2, pi2, pv3,
                                                   idx_fin, packed,
                                                   wcount, work,
                                                   ovfcount, ovf_list);

    rescore_cand_kernel<<<2048, 256, 0, stream>>>(X, C, x_sq, c_sq,
                                                  work, wcount, packed);
    rescore_ovf_kernel<<<2048, 256, 0, stream>>>(X, C, x_sq, c_sq,
                                                 ovf_list, ovfcount, packed);

    writeback_kernel<<<N_TOK / 256, 256, 0, stream>>>(packed, idx_fin);

    gather_kernel<<<N_TOK, 256, 0, stream>>>(idx_fin, table, bias, out);
}